// Round 1
// baseline (2574.066 us; speedup 1.0000x reference)
//
#include <hip/hip_runtime.h>

#define T_TOKENS 32768
#define DIM 512
#define FDIM 2048
#define NEXP 8

typedef __attribute__((ext_vector_type(4))) float f32x4;
typedef __attribute__((ext_vector_type(8))) short bf16x8;
typedef __attribute__((ext_vector_type(4))) short bf16x4;

__device__ __forceinline__ unsigned short f2bf(float f) {
  unsigned int u = __float_as_uint(f);
  u += 0x7FFFu + ((u >> 16) & 1u);   // round-to-nearest-even
  return (unsigned short)(u >> 16);
}

// in: [E][R][C] fp32 row-major  ->  out: [E][C][R] bf16
__global__ void transpose_cvt_kernel(const float* __restrict__ in,
                                     unsigned short* __restrict__ outp,
                                     int R, int C) {
  __shared__ unsigned short tileS[32][33];
  const int lx = threadIdx.x & 31, ly = threadIdx.x >> 5;
  const long e = blockIdx.z;
  const float* src = in + (e * (long)R + blockIdx.y * 32) * (long)C + blockIdx.x * 32;
  #pragma unroll
  for (int r = ly; r < 32; r += 8)
    tileS[r][lx] = f2bf(src[(long)r * C + lx]);
  __syncthreads();
  unsigned short* dst = outp + (e * (long)C + blockIdx.x * 32) * (long)R + blockIdx.y * 32;
  #pragma unroll
  for (int r = ly; r < 32; r += 8)
    dst[(long)r * R + lx] = tileS[lx][r];
}

__global__ void router_kernel(const float* __restrict__ x, const float* __restrict__ Wr,
                              const float* __restrict__ br, int* __restrict__ counts,
                              int* __restrict__ tok_list, float* __restrict__ wt_list) {
  __shared__ float WrS[NEXP][DIM];   // transposed: conflict-free stride-1 reads
  const int tid = threadIdx.x;
  for (int i = tid; i < NEXP * DIM; i += 256) {
    int e = i >> 9, d = i & (DIM - 1);
    WrS[e][d] = Wr[d * NEXP + e];
  }
  __syncthreads();
  const int wave = tid >> 6, lane = tid & 63;
  const int t = blockIdx.x * 4 + wave;
  const float* xr = x + (long)t * DIM;
  float acc[NEXP];
  #pragma unroll
  for (int e = 0; e < NEXP; e++) acc[e] = 0.f;
  #pragma unroll
  for (int it = 0; it < DIM / 64; it++) {
    int d = lane + it * 64;
    float xv = xr[d];
    #pragma unroll
    for (int e = 0; e < NEXP; e++) acc[e] += xv * WrS[e][d];
  }
  #pragma unroll
  for (int e = 0; e < NEXP; e++) {
    float v = acc[e];
    #pragma unroll
    for (int off = 32; off > 0; off >>= 1) v += __shfl_xor(v, off, 64);
    acc[e] = v;
  }
  if (lane == 0) {
    float l[NEXP];
    #pragma unroll
    for (int e = 0; e < NEXP; e++) l[e] = acc[e] + br[e];
    int e0 = 0; float v0 = l[0];
    #pragma unroll
    for (int e = 1; e < NEXP; e++) if (l[e] > v0) { v0 = l[e]; e0 = e; }
    int e1 = -1; float v1 = -3.4e38f;
    #pragma unroll
    for (int e = 0; e < NEXP; e++) if (e != e0 && l[e] > v1) { v1 = l[e]; e1 = e; }
    // softmax denominators cancel in the top-k renormalization:
    float w0 = 1.f / (1.f + expf(v1 - v0));
    float w1 = 1.f - w0;
    int s0 = atomicAdd(&counts[e0], 1);
    tok_list[e0 * T_TOKENS + s0] = t; wt_list[e0 * T_TOKENS + s0] = w0;
    int s1 = atomicAdd(&counts[e1], 1);
    tok_list[e1 * T_TOKENS + s1] = t; wt_list[e1 * T_TOKENS + s1] = w1;
  }
}

struct FfnSmem {
  unsigned short Xs[64][520];   // 66,560 B  (pad 512->520: 2-way banks, 16B-aligned rows)
  unsigned short W1s[128][72];  // 18,432 B  (Kc=64 pad->72)
  unsigned short Hs[64][136];   // 17,408 B  (BF=128 pad->136)
  unsigned short Bs2[512][36];  // 36,864 B  (Kc2=32 pad->36, rows 72B -> b64 access)
  int   tokS[64];
  float wtS[64];
};                               // total 139,776 B < 160 KB

__global__ __launch_bounds__(512, 2) void ffn_kernel(
    const float* __restrict__ x,
    const unsigned short* __restrict__ W1t,   // [E][F][D] bf16
    const unsigned short* __restrict__ W2t,   // [E][D][F] bf16
    const float* __restrict__ b1, const float* __restrict__ b2,
    const int* __restrict__ counts,
    const int* __restrict__ tok_list, const float* __restrict__ wt_list,
    float* __restrict__ out) {
  __shared__ FfnSmem sm;
  const int e = blockIdx.y;
  const int cnt = counts[e];
  const int m0 = blockIdx.x * 64;
  if (m0 >= cnt) return;
  const int rows = min(64, cnt - m0);

  const int tid = threadIdx.x;
  const int wave = tid >> 6, lane = tid & 63;
  const int g = lane >> 4, ln = lane & 15;

  if (tid < 64) {
    int tk = 0; float w = 0.f;
    if (tid < rows) {
      tk = tok_list[e * T_TOKENS + m0 + tid];
      w  = wt_list[e * T_TOKENS + m0 + tid];
    }
    sm.tokS[tid] = tk; sm.wtS[tid] = w;
  }
  __syncthreads();

  // stage gathered X tile (fp32 -> bf16), 64 rows x 512
  #pragma unroll 4
  for (int c = tid; c < 64 * 128; c += 512) {
    int r = c >> 7, q = c & 127;
    ushort4 bv;
    if (r < rows) {
      const float4 v = *(const float4*)(x + (long)sm.tokS[r] * DIM + q * 4);
      bv.x = f2bf(v.x); bv.y = f2bf(v.y); bv.z = f2bf(v.z); bv.w = f2bf(v.w);
    } else {
      bv.x = 0; bv.y = 0; bv.z = 0; bv.w = 0;
    }
    *(ushort4*)&sm.Xs[r][q * 4] = bv;
  }

  const f32x4 zero4 = {0.f, 0.f, 0.f, 0.f};
  f32x4 Yacc[4][4];
  #pragma unroll
  for (int a = 0; a < 4; a++)
    #pragma unroll
    for (int b = 0; b < 4; b++) Yacc[a][b] = zero4;

  const int mw = wave >> 2, nw = wave & 3;   // GEMM1 wave grid: 2 (m) x 4 (n)
  const unsigned short* W1e = W1t + (long)e * FDIM * DIM;
  const unsigned short* W2e = W2t + (long)e * DIM * FDIM;

  for (int fc = 0; fc < FDIM; fc += 128) {
    f32x4 Hacc[2][2];
    Hacc[0][0] = zero4; Hacc[0][1] = zero4; Hacc[1][0] = zero4; Hacc[1][1] = zero4;

    for (int kc = 0; kc < DIM; kc += 64) {
      __syncthreads();   // W1s safe to overwrite (also fences Xs staging on first iter)
      #pragma unroll
      for (int c2 = tid; c2 < 128 * 8; c2 += 512) {
        int f = c2 >> 3, dc = c2 & 7;
        bf16x8 v = *(const bf16x8*)(W1e + (long)(fc + f) * DIM + kc + dc * 8);
        *(bf16x8*)&sm.W1s[f][dc * 8] = v;
      }
      __syncthreads();
      #pragma unroll
      for (int ks = 0; ks < 2; ks++) {
        bf16x8 af0 = *(const bf16x8*)&sm.Xs[mw * 32 + ln][kc + ks * 32 + g * 8];
        bf16x8 af1 = *(const bf16x8*)&sm.Xs[mw * 32 + 16 + ln][kc + ks * 32 + g * 8];
        bf16x8 bg0 = *(const bf16x8*)&sm.W1s[nw * 32 + ln][ks * 32 + g * 8];
        bf16x8 bg1 = *(const bf16x8*)&sm.W1s[nw * 32 + 16 + ln][ks * 32 + g * 8];
        Hacc[0][0] = __builtin_amdgcn_mfma_f32_16x16x32_bf16(af0, bg0, Hacc[0][0], 0, 0, 0);
        Hacc[0][1] = __builtin_amdgcn_mfma_f32_16x16x32_bf16(af0, bg1, Hacc[0][1], 0, 0, 0);
        Hacc[1][0] = __builtin_amdgcn_mfma_f32_16x16x32_bf16(af1, bg0, Hacc[1][0], 0, 0, 0);
        Hacc[1][1] = __builtin_amdgcn_mfma_f32_16x16x32_bf16(af1, bg1, Hacc[1][1], 0, 0, 0);
      }
    }

    // bias + relu -> Hs (C-layout: col=lane&15, row=(lane>>4)*4+i)
    float b1v0 = b1[e * FDIM + fc + nw * 32 + ln];
    float b1v1 = b1[e * FDIM + fc + nw * 32 + 16 + ln];
    #pragma unroll
    for (int mt = 0; mt < 2; mt++)
      #pragma unroll
      for (int nt = 0; nt < 2; nt++) {
        int rb = mw * 32 + mt * 16 + g * 4;
        int cb = nw * 32 + nt * 16 + ln;
        float bv = nt ? b1v1 : b1v0;
        #pragma unroll
        for (int i = 0; i < 4; i++) {
          float v = Hacc[mt][nt][i] + bv;
          sm.Hs[rb + i][cb] = f2bf(fmaxf(v, 0.f));
        }
      }

    #pragma unroll
    for (int kc2 = 0; kc2 < 128; kc2 += 32) {
      __syncthreads();   // Bs2 safe to overwrite; first iter also fences Hs writes
      #pragma unroll
      for (int c2 = tid; c2 < 512 * 4; c2 += 512) {
        int d = c2 >> 2, q = c2 & 3;
        bf16x8 v = *(const bf16x8*)(W2e + (long)d * FDIM + fc + kc2 + q * 8);
        bf16x4 lo = __builtin_shufflevector(v, v, 0, 1, 2, 3);
        bf16x4 hi = __builtin_shufflevector(v, v, 4, 5, 6, 7);
        *(bf16x4*)&sm.Bs2[d][q * 8] = lo;
        *(bf16x4*)&sm.Bs2[d][q * 8 + 4] = hi;
      }
      __syncthreads();
      bf16x8 ha[4], wb[4];
      #pragma unroll
      for (int mt = 0; mt < 4; mt++)
        ha[mt] = *(const bf16x8*)&sm.Hs[mt * 16 + ln][kc2 + g * 8];
      #pragma unroll
      for (int nt = 0; nt < 4; nt++) {
        const unsigned short* p = &sm.Bs2[wave * 64 + nt * 16 + ln][g * 8];
        bf16x4 lo = *(const bf16x4*)p;
        bf16x4 hi = *(const bf16x4*)(p + 4);
        wb[nt] = __builtin_shufflevector(lo, hi, 0, 1, 2, 3, 4, 5, 6, 7);
      }
      #pragma unroll
      for (int mt = 0; mt < 4; mt++)
        #pragma unroll
        for (int nt = 0; nt < 4; nt++)
          Yacc[mt][nt] = __builtin_amdgcn_mfma_f32_16x16x32_bf16(ha[mt], wb[nt], Yacc[mt][nt], 0, 0, 0);
    }
  }

  // epilogue: (Y + b2) * token_weight -> atomicAdd into out
  #pragma unroll
  for (int nt = 0; nt < 4; nt++) {
    int d = wave * 64 + nt * 16 + ln;
    float b2v = b2[e * DIM + d];
    #pragma unroll
    for (int mt = 0; mt < 4; mt++) {
      #pragma unroll
      for (int i = 0; i < 4; i++) {
        int m = mt * 16 + g * 4 + i;
        if (m < rows) {
          float v = (Yacc[mt][nt][i] + b2v) * sm.wtS[m];
          atomicAdd(out + (long)sm.tokS[m] * DIM + d, v);
        }
      }
    }
  }
}

extern "C" void kernel_launch(void* const* d_in, const int* in_sizes, int n_in,
                              void* d_out, int out_size, void* d_ws, size_t ws_size,
                              hipStream_t stream) {
  (void)in_sizes; (void)n_in; (void)out_size; (void)ws_size;
  const float* x  = (const float*)d_in[0];
  const float* Wr = (const float*)d_in[1];
  const float* br = (const float*)d_in[2];
  const float* W1 = (const float*)d_in[3];
  const float* b1 = (const float*)d_in[4];
  const float* W2 = (const float*)d_in[5];
  const float* b2 = (const float*)d_in[6];
  float* out = (float*)d_out;

  char* ws = (char*)d_ws;
  int*            counts   = (int*)(ws);                      //      1,024 B
  int*            tok_list = (int*)(ws + 1024);               //  1,048,576 B
  float*          wt_list  = (float*)(ws + 1049600);          //  1,048,576 B
  unsigned short* W1t      = (unsigned short*)(ws + 2098176); // 16,777,216 B
  unsigned short* W2t      = (unsigned short*)(ws + 18875392);// 16,777,216 B  (end ~35.7 MB)

  hipMemsetAsync(counts, 0, 1024, stream);
  hipMemsetAsync(out, 0, (size_t)T_TOKENS * DIM * sizeof(float), stream);
  // W1 [E][D][F] -> W1t [E][F][D]
  transpose_cvt_kernel<<<dim3(FDIM / 32, DIM / 32, NEXP), 256, 0, stream>>>(W1, W1t, DIM, FDIM);
  // W2 [E][F][D] -> W2t [E][D][F]
  transpose_cvt_kernel<<<dim3(DIM / 32, FDIM / 32, NEXP), 256, 0, stream>>>(W2, W2t, FDIM, DIM);
  router_kernel<<<T_TOKENS / 4, 256, 0, stream>>>(x, Wr, br, counts, tok_list, wt_list);
  ffn_kernel<<<dim3(T_TOKENS / 64, NEXP), 512, 0, stream>>>(
      x, W1t, W2t, b1, b2, counts, tok_list, wt_list, out);
}

// Round 2
// 1270.352 us; speedup vs baseline: 2.0263x; 2.0263x over previous
//
#include <hip/hip_runtime.h>

#define T_TOKENS 32768
#define DIM 512
#define FDIM 2048
#define NEXP 8

typedef __attribute__((ext_vector_type(4))) float f32x4;
typedef __attribute__((ext_vector_type(8))) short bf16x8;

__device__ __forceinline__ unsigned short f2bf(float f) {
  unsigned int u = __float_as_uint(f);
  u += 0x7FFFu + ((u >> 16) & 1u);   // round-to-nearest-even
  return (unsigned short)(u >> 16);
}

// in: [E][R][C] fp32 row-major  ->  out: [E][C][R] bf16
__global__ void transpose_cvt_kernel(const float* __restrict__ in,
                                     unsigned short* __restrict__ outp,
                                     int R, int C) {
  __shared__ unsigned short tileS[32][33];
  const int lx = threadIdx.x & 31, ly = threadIdx.x >> 5;
  const long e = blockIdx.z;
  const float* src = in + (e * (long)R + blockIdx.y * 32) * (long)C + blockIdx.x * 32;
  #pragma unroll
  for (int r = ly; r < 32; r += 8)
    tileS[r][lx] = f2bf(src[(long)r * C + lx]);
  __syncthreads();
  unsigned short* dst = outp + (e * (long)C + blockIdx.x * 32) * (long)R + blockIdx.y * 32;
  #pragma unroll
  for (int r = ly; r < 32; r += 8)
    dst[(long)r * R + lx] = tileS[lx][r];
}

// one thread per token; per-block LDS histogram -> 8 global atomics per block
__global__ void router_kernel(const float* __restrict__ x, const float* __restrict__ Wr,
                              const float* __restrict__ br, int* __restrict__ counts,
                              int* __restrict__ tok_list, float* __restrict__ wt_list) {
  __shared__ float WrS[NEXP][DIM];   // transposed: broadcast reads (all lanes same addr)
  __shared__ int lcnt[NEXP];
  __shared__ int lbase[NEXP];
  const int tid = threadIdx.x;   // 256
  for (int i = tid; i < NEXP * DIM; i += 256) {
    int e = i >> 9, d = i & (DIM - 1);
    WrS[e][d] = Wr[d * NEXP + e];
  }
  if (tid < NEXP) lcnt[tid] = 0;
  __syncthreads();

  const int t = blockIdx.x * 256 + tid;
  const float* xr = x + (long)t * DIM;
  float acc[NEXP];
  #pragma unroll
  for (int e = 0; e < NEXP; e++) acc[e] = br[e];
  for (int d = 0; d < DIM; d += 4) {
    const float4 xv = *(const float4*)(xr + d);
    #pragma unroll
    for (int e = 0; e < NEXP; e++)
      acc[e] += xv.x * WrS[e][d] + xv.y * WrS[e][d + 1] +
                xv.z * WrS[e][d + 2] + xv.w * WrS[e][d + 3];
  }
  int e0 = 0; float v0 = acc[0];
  #pragma unroll
  for (int e = 1; e < NEXP; e++) if (acc[e] > v0) { v0 = acc[e]; e0 = e; }
  int e1 = -1; float v1 = -3.4e38f;
  #pragma unroll
  for (int e = 0; e < NEXP; e++) if (e != e0 && acc[e] > v1) { v1 = acc[e]; e1 = e; }
  // softmax denominators cancel in the top-k renormalization:
  float w0 = 1.f / (1.f + __expf(v1 - v0));
  float w1 = 1.f - w0;

  int l0 = atomicAdd(&lcnt[e0], 1);
  int l1 = atomicAdd(&lcnt[e1], 1);
  __syncthreads();
  if (tid < NEXP) lbase[tid] = atomicAdd(&counts[tid], lcnt[tid]);
  __syncthreads();
  int s0 = lbase[e0] + l0;
  tok_list[e0 * T_TOKENS + s0] = t; wt_list[e0 * T_TOKENS + s0] = w0;
  int s1 = lbase[e1] + l1;
  tok_list[e1 * T_TOKENS + s1] = t; wt_list[e1 * T_TOKENS + s1] = w1;
}

struct FfnSmem {
  unsigned short Xs[64][520];   // 66,560 B (pad 512->520: conflict-free b128 frag reads)
  unsigned short Hs[64][72];    //  9,216 B (fc-chunk 64, pad ->72)
  int   tokS[64];
  float wtS[64];
};                               // 76,288 B -> 2 blocks/CU

__global__ __launch_bounds__(512, 4) void ffn_kernel(
    const float* __restrict__ x,
    const unsigned short* __restrict__ W1t,   // [E][F][D] bf16
    const unsigned short* __restrict__ W2t,   // [E][D][F] bf16
    const float* __restrict__ b1, const float* __restrict__ b2,
    const int* __restrict__ counts,
    const int* __restrict__ tok_list, const float* __restrict__ wt_list,
    float* __restrict__ out) {
  __shared__ FfnSmem sm;
  const int e = blockIdx.y;
  const int cnt = counts[e];
  const int m0 = blockIdx.x * 64;
  if (m0 >= cnt) return;
  const int rows = min(64, cnt - m0);

  const int tid = threadIdx.x;
  const int wave = tid >> 6, lane = tid & 63;
  const int g = lane >> 4, ln = lane & 15;
  const int mw = wave >> 2, nw = wave & 3;   // GEMM1 wave grid: 2(m) x 4(n), tile 32x16

  if (tid < 64) {
    int tk = 0; float w = 0.f;
    if (tid < rows) {
      tk = tok_list[e * T_TOKENS + m0 + tid];
      w  = wt_list[e * T_TOKENS + m0 + tid];
    }
    sm.tokS[tid] = tk; sm.wtS[tid] = w;
  }
  __syncthreads();

  // stage gathered X tile (fp32 -> bf16), 64 rows x 512
  #pragma unroll 4
  for (int c = tid; c < 64 * 128; c += 512) {
    int r = c >> 7, q = c & 127;
    ushort4 bv;
    if (r < rows) {
      const float4 v = *(const float4*)(x + (long)sm.tokS[r] * DIM + q * 4);
      bv.x = f2bf(v.x); bv.y = f2bf(v.y); bv.z = f2bf(v.z); bv.w = f2bf(v.w);
    } else {
      bv.x = 0; bv.y = 0; bv.z = 0; bv.w = 0;
    }
    *(ushort4*)&sm.Xs[r][q * 4] = bv;
  }
  __syncthreads();

  const f32x4 zero4 = {0.f, 0.f, 0.f, 0.f};
  f32x4 Yacc[4][4];
  #pragma unroll
  for (int a = 0; a < 4; a++)
    #pragma unroll
    for (int b = 0; b < 4; b++) Yacc[a][b] = zero4;

  const unsigned short* W1e = W1t + (long)e * FDIM * DIM;
  const unsigned short* W2e = W2t + (long)e * DIM * FDIM;
  // per-lane weight base pointers (B-fragments loaded straight from global)
  const unsigned short* w1lane = W1e + (long)(nw * 16 + ln) * DIM + g * 8;
  const unsigned short* w2lane[4];
  #pragma unroll
  for (int nt = 0; nt < 4; nt++)
    w2lane[nt] = W2e + (long)(wave * 64 + nt * 16 + ln) * FDIM + g * 8;
  const float b1base = 0.f;  (void)b1base;

  for (int fc = 0; fc < FDIM; fc += 64) {
    // ---- GEMM1: H(64x64) = X(64x512) * W1t-chunk^T, B-frags from global ----
    f32x4 Hacc0 = zero4, Hacc1 = zero4;
    const unsigned short* w1p = w1lane + (long)fc * DIM;
    #pragma unroll 4
    for (int kc = 0; kc < DIM; kc += 32) {
      bf16x8 bg  = *(const bf16x8*)(w1p + kc);
      bf16x8 af0 = *(const bf16x8*)&sm.Xs[mw * 32 + ln][kc + g * 8];
      bf16x8 af1 = *(const bf16x8*)&sm.Xs[mw * 32 + 16 + ln][kc + g * 8];
      Hacc0 = __builtin_amdgcn_mfma_f32_16x16x32_bf16(af0, bg, Hacc0, 0, 0, 0);
      Hacc1 = __builtin_amdgcn_mfma_f32_16x16x32_bf16(af1, bg, Hacc1, 0, 0, 0);
    }

    __syncthreads();   // all waves done reading Hs of previous fc
    // bias + relu -> Hs (C-layout: row m = g*4+i, col n = ln)
    {
      float b1v = b1[e * FDIM + fc + nw * 16 + ln];
      #pragma unroll
      for (int i = 0; i < 4; i++) {
        float v0h = Hacc0[i] + b1v;
        float v1h = Hacc1[i] + b1v;
        sm.Hs[mw * 32 + g * 4 + i][nw * 16 + ln]      = f2bf(fmaxf(v0h, 0.f));
        sm.Hs[mw * 32 + 16 + g * 4 + i][nw * 16 + ln] = f2bf(fmaxf(v1h, 0.f));
      }
    }
    __syncthreads();   // Hs ready

    // ---- GEMM2: Y(64x512) += H(64x64) * W2t-chunk^T, B-frags from global ----
    #pragma unroll
    for (int kc2 = 0; kc2 < 64; kc2 += 32) {
      bf16x8 ha[4];
      #pragma unroll
      for (int mt = 0; mt < 4; mt++)
        ha[mt] = *(const bf16x8*)&sm.Hs[mt * 16 + ln][kc2 + g * 8];
      #pragma unroll
      for (int nt = 0; nt < 4; nt++) {
        bf16x8 wb = *(const bf16x8*)(w2lane[nt] + fc + kc2);
        #pragma unroll
        for (int mt = 0; mt < 4; mt++)
          Yacc[mt][nt] = __builtin_amdgcn_mfma_f32_16x16x32_bf16(ha[mt], wb, Yacc[mt][nt], 0, 0, 0);
      }
    }
  }

  // epilogue: (Y + b2) * token_weight -> atomicAdd into out
  #pragma unroll
  for (int nt = 0; nt < 4; nt++) {
    int d = wave * 64 + nt * 16 + ln;
    float b2v = b2[e * DIM + d];
    #pragma unroll
    for (int mt = 0; mt < 4; mt++) {
      #pragma unroll
      for (int i = 0; i < 4; i++) {
        int m = mt * 16 + g * 4 + i;
        if (m < rows) {
          float v = (Yacc[mt][nt][i] + b2v) * sm.wtS[m];
          atomicAdd(out + (long)sm.tokS[m] * DIM + d, v);
        }
      }
    }
  }
}

extern "C" void kernel_launch(void* const* d_in, const int* in_sizes, int n_in,
                              void* d_out, int out_size, void* d_ws, size_t ws_size,
                              hipStream_t stream) {
  (void)in_sizes; (void)n_in; (void)out_size; (void)ws_size;
  const float* x  = (const float*)d_in[0];
  const float* Wr = (const float*)d_in[1];
  const float* br = (const float*)d_in[2];
  const float* W1 = (const float*)d_in[3];
  const float* b1 = (const float*)d_in[4];
  const float* W2 = (const float*)d_in[5];
  const float* b2 = (const float*)d_in[6];
  float* out = (float*)d_out;

  char* ws = (char*)d_ws;
  int*            counts   = (int*)(ws);                      //      1,024 B
  int*            tok_list = (int*)(ws + 1024);               //  1,048,576 B
  float*          wt_list  = (float*)(ws + 1049600);          //  1,048,576 B
  unsigned short* W1t      = (unsigned short*)(ws + 2098176); // 16,777,216 B
  unsigned short* W2t      = (unsigned short*)(ws + 18875392);// 16,777,216 B  (end ~35.7 MB)

  hipMemsetAsync(counts, 0, 1024, stream);
  hipMemsetAsync(out, 0, (size_t)T_TOKENS * DIM * sizeof(float), stream);
  // W1 [E][D][F] -> W1t [E][F][D]
  transpose_cvt_kernel<<<dim3(FDIM / 32, DIM / 32, NEXP), 256, 0, stream>>>(W1, W1t, DIM, FDIM);
  // W2 [E][F][D] -> W2t [E][D][F]
  transpose_cvt_kernel<<<dim3(DIM / 32, FDIM / 32, NEXP), 256, 0, stream>>>(W2, W2t, FDIM, DIM);
  router_kernel<<<T_TOKENS / 256, 256, 0, stream>>>(x, Wr, br, counts, tok_list, wt_list);
  ffn_kernel<<<dim3(T_TOKENS / 64, NEXP), 512, 0, stream>>>(
      x, W1t, W2t, b1, b2, counts, tok_list, wt_list, out);
}

// Round 3
// 1007.795 us; speedup vs baseline: 2.5542x; 1.2605x over previous
//
#include <hip/hip_runtime.h>

#define T_TOKENS 32768
#define DIM 512
#define FDIM 2048
#define NEXP 8

typedef __attribute__((ext_vector_type(4))) float f32x4;
typedef __attribute__((ext_vector_type(8))) short bf16x8;

__device__ __forceinline__ unsigned short f2bf(float f) {
  unsigned int u = __float_as_uint(f);
  u += 0x7FFFu + ((u >> 16) & 1u);   // round-to-nearest-even
  return (unsigned short)(u >> 16);
}

// Pack W1 [E][D][F] fp32 -> W1p fragment-linear bf16:
// task t = ((e*128 + ft)*16 + kci); lane l owns 8 shorts:
//   W1p[t*512 + l*8 + j] = bf16(W1[e][kci*32 + (l>>4)*8 + j][ft*16 + (l&15)])
__global__ void pack_w1_kernel(const float* __restrict__ W1, unsigned short* __restrict__ W1p) {
  const int t = blockIdx.x * 4 + (threadIdx.x >> 6);
  const int lane = threadIdx.x & 63;
  const int kci = t & 15, ft = (t >> 4) & 127, e = t >> 11;
  const int f = ft * 16 + (lane & 15);
  const int d0 = kci * 32 + (lane >> 4) * 8;
  const float* src = W1 + ((long)e * DIM + d0) * FDIM + f;
  bf16x8 v;
  #pragma unroll
  for (int j = 0; j < 8; j++) v[j] = (short)f2bf(src[(long)j * FDIM]);
  *(bf16x8*)(W1p + (long)t * 512 + lane * 8) = v;
}

// Pack W2 [E][F][D] fp32 -> W2p fragment-linear bf16:
// task t = ((e*64 + kc2i)*32 + dt); lane l owns 8 shorts:
//   W2p[t*512 + l*8 + j] = bf16(W2[e][kc2i*32 + (l>>4)*8 + j][dt*16 + (l&15)])
__global__ void pack_w2_kernel(const float* __restrict__ W2, unsigned short* __restrict__ W2p) {
  const int t = blockIdx.x * 4 + (threadIdx.x >> 6);
  const int lane = threadIdx.x & 63;
  const int dt = t & 31, kc2i = (t >> 5) & 63, e = t >> 11;
  const int d = dt * 16 + (lane & 15);
  const int f0 = kc2i * 32 + (lane >> 4) * 8;
  const float* src = W2 + ((long)e * FDIM + f0) * DIM + d;
  bf16x8 v;
  #pragma unroll
  for (int j = 0; j < 8; j++) v[j] = (short)f2bf(src[(long)j * DIM]);
  *(bf16x8*)(W2p + (long)t * 512 + lane * 8) = v;
}

// one thread per token; per-block LDS histogram -> 8 global atomics per block
__global__ void router_kernel(const float* __restrict__ x, const float* __restrict__ Wr,
                              const float* __restrict__ br, int* __restrict__ counts,
                              int* __restrict__ tok_list, float* __restrict__ wt_list) {
  __shared__ float WrS[NEXP][DIM];
  __shared__ int lcnt[NEXP];
  __shared__ int lbase[NEXP];
  const int tid = threadIdx.x;   // 256
  for (int i = tid; i < NEXP * DIM; i += 256) {
    int e = i >> 9, d = i & (DIM - 1);
    WrS[e][d] = Wr[d * NEXP + e];
  }
  if (tid < NEXP) lcnt[tid] = 0;
  __syncthreads();

  const int t = blockIdx.x * 256 + tid;
  const float* xr = x + (long)t * DIM;
  float acc[NEXP];
  #pragma unroll
  for (int e = 0; e < NEXP; e++) acc[e] = br[e];
  for (int d = 0; d < DIM; d += 4) {
    const float4 xv = *(const float4*)(xr + d);
    #pragma unroll
    for (int e = 0; e < NEXP; e++)
      acc[e] += xv.x * WrS[e][d] + xv.y * WrS[e][d + 1] +
                xv.z * WrS[e][d + 2] + xv.w * WrS[e][d + 3];
  }
  int e0 = 0; float v0 = acc[0];
  #pragma unroll
  for (int e = 1; e < NEXP; e++) if (acc[e] > v0) { v0 = acc[e]; e0 = e; }
  int e1 = -1; float v1 = -3.4e38f;
  #pragma unroll
  for (int e = 0; e < NEXP; e++) if (e != e0 && acc[e] > v1) { v1 = acc[e]; e1 = e; }
  float w0 = 1.f / (1.f + __expf(v1 - v0));
  float w1 = 1.f - w0;

  int l0 = atomicAdd(&lcnt[e0], 1);
  int l1 = atomicAdd(&lcnt[e1], 1);
  __syncthreads();
  if (tid < NEXP) lbase[tid] = atomicAdd(&counts[tid], lcnt[tid]);
  __syncthreads();
  int s0 = lbase[e0] + l0;
  tok_list[e0 * T_TOKENS + s0] = t; wt_list[e0 * T_TOKENS + s0] = w0;
  int s1 = lbase[e1] + l1;
  tok_list[e1 * T_TOKENS + s1] = t; wt_list[e1 * T_TOKENS + s1] = w1;
}

// LDS: Xs 64x512 bf16 XOR-swizzled (64 KB) + Hs 64x128 bf16 XOR-swizzled (16 KB) = 80 KB
// -> 2 blocks/CU. Swizzle: 16B chunk c of row r stored at chunk (c ^ (r&7)).
__global__ __launch_bounds__(512, 4) void ffn_kernel(
    const float* __restrict__ x,
    const unsigned short* __restrict__ W1p,
    const unsigned short* __restrict__ W2p,
    const float* __restrict__ b1, const float* __restrict__ b2,
    const int* __restrict__ counts,
    const int* __restrict__ tok_list, const float* __restrict__ wt_list,
    float* __restrict__ out) {
  __shared__ unsigned short Xs[64 * 512];
  __shared__ unsigned short Hs[64 * 128];

  const int e = blockIdx.x & 7;        // expert -> XCD pinning (round-robin heuristic)
  const int tile = blockIdx.x >> 3;
  const int cnt = counts[e];
  const int m0 = tile * 64;
  if (m0 >= cnt) return;
  const int rows = min(64, cnt - m0);

  const int tid = threadIdx.x;
  const int wave = tid >> 6, lane = tid & 63;
  const int g = lane >> 4, ln = lane & 15;
  const int mw = wave >> 2, nw = wave & 3;   // GEMM1 wave grid: 2(m) x 4(n), tile 32x32

  // stage gathered X tile (fp32 -> bf16), swizzled
  #pragma unroll 4
  for (int c = tid; c < 64 * 128; c += 512) {
    int r = c >> 7, q = c & 127;
    ushort4 bv = {0, 0, 0, 0};
    if (r < rows) {
      int tk = tok_list[e * T_TOKENS + m0 + r];
      const float4 v = *(const float4*)(x + (long)tk * DIM + q * 4);
      bv.x = f2bf(v.x); bv.y = f2bf(v.y); bv.z = f2bf(v.z); bv.w = f2bf(v.w);
    }
    int addr = r * 512 + ((((q >> 1) ^ (r & 7)) << 3) | ((q & 1) << 2));
    *(ushort4*)&Xs[addr] = bv;
  }
  __syncthreads();

  const f32x4 zero4 = {0.f, 0.f, 0.f, 0.f};
  f32x4 Yacc[4][4];
  #pragma unroll
  for (int a = 0; a < 4; a++)
    #pragma unroll
    for (int b = 0; b < 4; b++) Yacc[a][b] = zero4;

  // GEMM1 A-frag addresses (swizzle bits depend only on ln&7)
  const int xsw = ln & 7;
  const int xbase0 = (mw * 32 + ln) * 512;

  for (int fc = 0; fc < FDIM; fc += 128) {
    // ---- GEMM1: H(64x128) = X(64x512) * W1-chunk, B-frags coalesced from W1p ----
    f32x4 H00 = zero4, H01 = zero4, H10 = zero4, H11 = zero4;
    const unsigned short* w1b =
        W1p + ((long)(e * 128 + (fc >> 4) + nw * 2) * 16) * 512 + lane * 8;
    #pragma unroll
    for (int kci = 0; kci < 16; kci++) {
      bf16x8 bg0 = *(const bf16x8*)(w1b + kci * 512);
      bf16x8 bg1 = *(const bf16x8*)(w1b + (16 + kci) * 512);
      int xo = ((kci * 4 + g) ^ xsw) << 3;
      bf16x8 af0 = *(const bf16x8*)&Xs[xbase0 + xo];
      bf16x8 af1 = *(const bf16x8*)&Xs[xbase0 + 16 * 512 + xo];
      H00 = __builtin_amdgcn_mfma_f32_16x16x32_bf16(af0, bg0, H00, 0, 0, 0);
      H01 = __builtin_amdgcn_mfma_f32_16x16x32_bf16(af0, bg1, H01, 0, 0, 0);
      H10 = __builtin_amdgcn_mfma_f32_16x16x32_bf16(af1, bg0, H10, 0, 0, 0);
      H11 = __builtin_amdgcn_mfma_f32_16x16x32_bf16(af1, bg1, H11, 0, 0, 0);
    }

    __syncthreads();   // all waves done reading Hs of previous fc-iter
    {
      float b1v0 = b1[e * FDIM + fc + nw * 32 + ln];
      float b1v1 = b1[e * FDIM + fc + nw * 32 + 16 + ln];
      #pragma unroll
      for (int mi = 0; mi < 2; mi++) {
        #pragma unroll
        for (int ni = 0; ni < 2; ni++) {
          const f32x4& hv = mi ? (ni ? H11 : H10) : (ni ? H01 : H00);
          float bv = ni ? b1v1 : b1v0;
          int fl = nw * 32 + ni * 16 + ln;        // local f (0..127)
          #pragma unroll
          for (int i = 0; i < 4; i++) {
            int m = mw * 32 + mi * 16 + g * 4 + i;
            int addr = m * 128 + ((((fl >> 3) ^ (m & 7)) << 3) | (fl & 7));
            Hs[addr] = f2bf(fmaxf(hv[i] + bv, 0.f));
          }
        }
      }
    }
    __syncthreads();   // Hs ready

    // ---- GEMM2: Y(64x512) += H(64x128) * W2-chunk, B-frags coalesced from W2p ----
    #pragma unroll
    for (int kl = 0; kl < 4; kl++) {
      bf16x8 ha[4];
      #pragma unroll
      for (int mt = 0; mt < 4; mt++) {
        int m = mt * 16 + ln;
        ha[mt] = *(const bf16x8*)&Hs[m * 128 + ((((kl * 4 + g) ^ (m & 7)) << 3))];
      }
      const unsigned short* w2b =
          W2p + ((long)((e * 64 + (fc >> 5) + kl) * 32 + wave * 4) * 64 + lane) * 8;
      #pragma unroll
      for (int nt = 0; nt < 4; nt++) {
        bf16x8 wb = *(const bf16x8*)(w2b + nt * 512);
        #pragma unroll
        for (int mt = 0; mt < 4; mt++)
          Yacc[mt][nt] = __builtin_amdgcn_mfma_f32_16x16x32_bf16(ha[mt], wb, Yacc[mt][nt], 0, 0, 0);
      }
    }
  }

  // epilogue: (Y + b2) * token_weight -> atomicAdd into out
  #pragma unroll
  for (int mt = 0; mt < 4; mt++) {
    #pragma unroll
    for (int i = 0; i < 4; i++) {
      int m = mt * 16 + g * 4 + i;
      if (m < rows) {
        int   tk = tok_list[e * T_TOKENS + m0 + m];
        float w  = wt_list[e * T_TOKENS + m0 + m];
        #pragma unroll
        for (int nt = 0; nt < 4; nt++) {
          int d = (wave * 4 + nt) * 16 + ln;
          float v = (Yacc[mt][nt][i] + b2[e * DIM + d]) * w;
          atomicAdd(out + (long)tk * DIM + d, v);
        }
      }
    }
  }
}

extern "C" void kernel_launch(void* const* d_in, const int* in_sizes, int n_in,
                              void* d_out, int out_size, void* d_ws, size_t ws_size,
                              hipStream_t stream) {
  (void)in_sizes; (void)n_in; (void)out_size; (void)ws_size;
  const float* x  = (const float*)d_in[0];
  const float* Wr = (const float*)d_in[1];
  const float* br = (const float*)d_in[2];
  const float* W1 = (const float*)d_in[3];
  const float* b1 = (const float*)d_in[4];
  const float* W2 = (const float*)d_in[5];
  const float* b2 = (const float*)d_in[6];
  float* out = (float*)d_out;

  char* ws = (char*)d_ws;
  int*            counts   = (int*)(ws);                      //      1,024 B
  int*            tok_list = (int*)(ws + 1024);               //  1,048,576 B
  float*          wt_list  = (float*)(ws + 1049600);          //  1,048,576 B
  unsigned short* W1p      = (unsigned short*)(ws + 2098176); // 16,777,216 B
  unsigned short* W2p      = (unsigned short*)(ws + 18875392);// 16,777,216 B  (end ~35.7 MB)

  hipMemsetAsync(counts, 0, 1024, stream);
  hipMemsetAsync(out, 0, (size_t)T_TOKENS * DIM * sizeof(float), stream);
  pack_w1_kernel<<<4096, 256, 0, stream>>>(W1, W1p);
  pack_w2_kernel<<<4096, 256, 0, stream>>>(W2, W2p);
  router_kernel<<<T_TOKENS / 256, 256, 0, stream>>>(x, Wr, br, counts, tok_list, wt_list);
  ffn_kernel<<<T_TOKENS / 64 * NEXP, 512, 0, stream>>>(
      x, W1p, W2p, b1, b2, counts, tok_list, wt_list, out);
}

// Round 4
// 868.724 us; speedup vs baseline: 2.9630x; 1.1601x over previous
//
#include <hip/hip_runtime.h>

#define T_TOKENS 32768
#define DIM 512
#define FDIM 2048
#define NEXP 8

typedef __attribute__((ext_vector_type(4))) float f32x4;
typedef __attribute__((ext_vector_type(8))) short bf16x8;

__device__ __forceinline__ unsigned short f2bf(float f) {
  unsigned int u = __float_as_uint(f);
  u += 0x7FFFu + ((u >> 16) & 1u);   // round-to-nearest-even
  return (unsigned short)(u >> 16);
}

// Pack W1 [E][D][F] fp32 -> fragment-linear bf16, line-coalesced reads via LDS.
// W1p[((e*128+ft)*16+kci)*512 + l*8 + j] = bf16(W1[e][kci*32+(l>>4)*8+j][ft*16+(l&15)])
__global__ void pack_w1_kernel(const float* __restrict__ W1, unsigned short* __restrict__ W1p) {
  __shared__ float L[512][17];
  const int b = blockIdx.x;          // e*128 + ft
  const int e = b >> 7, ft = b & 127;
  const int t = threadIdx.x;         // 256
  const int c = t & 15, r0 = t >> 4;
  const float* src = W1 + (long)e * 512 * 2048 + ft * 16 + c;
  #pragma unroll
  for (int ch = 0; ch < 32; ch++) {
    int r = ch * 16 + r0;
    L[r][c] = src[(long)r * 2048];
  }
  __syncthreads();
  #pragma unroll
  for (int s = 0; s < 4; s++) {
    int slot = s * 256 + t;
    int kci = slot >> 6, l = slot & 63;
    unsigned short tmp[8];
    #pragma unroll
    for (int j = 0; j < 8; j++)
      tmp[j] = f2bf(L[kci * 32 + (l >> 4) * 8 + j][l & 15]);
    *(ushort4*)(W1p + ((long)b * 16 + kci) * 512 + l * 8)     = *(ushort4*)&tmp[0];
    *(ushort4*)(W1p + ((long)b * 16 + kci) * 512 + l * 8 + 4) = *(ushort4*)&tmp[4];
  }
}

// Pack W2 [E][F][D] fp32 -> fragment-linear bf16, line-coalesced reads via LDS.
// W2p[((e*64+kc2i)*32+dt)*512 + l*8 + j] = bf16(W2[e][kc2i*32+(l>>4)*8+j][dt*16+(l&15)])
__global__ void pack_w2_kernel(const float* __restrict__ W2, unsigned short* __restrict__ W2p) {
  __shared__ float L[512][17];
  const int b = blockIdx.x;          // e*32 + dt
  const int e = b >> 5, dt = b & 31;
  const int t = threadIdx.x;
  const int c = t & 15, r0 = t >> 4;
  for (int ch = 0; ch < 4; ch++) {   // f in chunks of 512
    if (ch) __syncthreads();
    const float* src = W2 + ((long)e * 2048 + ch * 512) * 512 + dt * 16 + c;
    #pragma unroll
    for (int cc = 0; cc < 32; cc++) {
      int r = cc * 16 + r0;
      L[r][c] = src[(long)r * 512];
    }
    __syncthreads();
    #pragma unroll
    for (int s = 0; s < 4; s++) {
      int slot = s * 256 + t;
      int kciL = slot >> 6, l = slot & 63;
      unsigned short tmp[8];
      #pragma unroll
      for (int j = 0; j < 8; j++)
        tmp[j] = f2bf(L[kciL * 32 + (l >> 4) * 8 + j][l & 15]);
      long tt = (long)(e * 64 + ch * 16 + kciL) * 32 + dt;
      *(ushort4*)(W2p + tt * 512 + l * 8)     = *(ushort4*)&tmp[0];
      *(ushort4*)(W2p + tt * 512 + l * 8 + 4) = *(ushort4*)&tmp[4];
    }
  }
}

// one thread per token; per-block LDS histogram -> 8 global atomics per block
__global__ void router_kernel(const float* __restrict__ x, const float* __restrict__ Wr,
                              const float* __restrict__ br, int* __restrict__ counts,
                              int* __restrict__ tok_list, float* __restrict__ wt_list) {
  __shared__ float WrS[NEXP][DIM];
  __shared__ int lcnt[NEXP];
  __shared__ int lbase[NEXP];
  const int tid = threadIdx.x;   // 256
  for (int i = tid; i < NEXP * DIM; i += 256) {
    int e = i >> 9, d = i & (DIM - 1);
    WrS[e][d] = Wr[d * NEXP + e];
  }
  if (tid < NEXP) lcnt[tid] = 0;
  __syncthreads();

  const int t = blockIdx.x * 256 + tid;
  const float* xr = x + (long)t * DIM;
  float acc[NEXP];
  #pragma unroll
  for (int e = 0; e < NEXP; e++) acc[e] = br[e];
  for (int d = 0; d < DIM; d += 4) {
    const float4 xv = *(const float4*)(xr + d);
    #pragma unroll
    for (int e = 0; e < NEXP; e++)
      acc[e] += xv.x * WrS[e][d] + xv.y * WrS[e][d + 1] +
                xv.z * WrS[e][d + 2] + xv.w * WrS[e][d + 3];
  }
  int e0 = 0; float v0 = acc[0];
  #pragma unroll
  for (int e = 1; e < NEXP; e++) if (acc[e] > v0) { v0 = acc[e]; e0 = e; }
  int e1 = -1; float v1 = -3.4e38f;
  #pragma unroll
  for (int e = 0; e < NEXP; e++) if (e != e0 && acc[e] > v1) { v1 = acc[e]; e1 = e; }
  float w0 = 1.f / (1.f + __expf(v1 - v0));
  float w1 = 1.f - w0;

  int l0 = atomicAdd(&lcnt[e0], 1);
  int l1 = atomicAdd(&lcnt[e1], 1);
  __syncthreads();
  if (tid < NEXP) lbase[tid] = atomicAdd(&counts[tid], lcnt[tid]);
  __syncthreads();
  int s0 = lbase[e0] + l0;
  tok_list[e0 * T_TOKENS + s0] = t; wt_list[e0 * T_TOKENS + s0] = w0;
  int s1 = lbase[e1] + l1;
  tok_list[e1 * T_TOKENS + s1] = t; wt_list[e1 * T_TOKENS + s1] = w1;
}

#define LD_W1(dst, base)                                        \
  _Pragma("unroll")                                             \
  for (int i = 0; i < 4; i++) {                                 \
    dst[i][0] = *(const bf16x8*)(w1b + (base + i) * 512);       \
    dst[i][1] = *(const bf16x8*)(w1b + (16 + base + i) * 512);  \
  }

#define MF_W1(src, base)                                                          \
  _Pragma("unroll")                                                               \
  for (int i = 0; i < 4; i++) {                                                   \
    int kci = base + i;                                                           \
    int xo = ((kci * 4 + g) ^ xsw) << 3;                                          \
    bf16x8 af0 = *(const bf16x8*)&Xs[xbase0 + xo];                                \
    bf16x8 af1 = *(const bf16x8*)&Xs[xbase0 + 16 * 512 + xo];                     \
    H00 = __builtin_amdgcn_mfma_f32_16x16x32_bf16(af0, src[i][0], H00, 0, 0, 0);  \
    H01 = __builtin_amdgcn_mfma_f32_16x16x32_bf16(af0, src[i][1], H01, 0, 0, 0);  \
    H10 = __builtin_amdgcn_mfma_f32_16x16x32_bf16(af1, src[i][0], H10, 0, 0, 0);  \
    H11 = __builtin_amdgcn_mfma_f32_16x16x32_bf16(af1, src[i][1], H11, 0, 0, 0);  \
  }

#define LD_W2(klbase)                                                             \
  _Pragma("unroll")                                                               \
  for (int kl = klbase; kl < klbase + 2; kl++) {                                  \
    const unsigned short* w2b =                                                   \
        W2p + ((long)((e * 64 + (fc >> 5) + kl) * 32 + wave * 4) * 64 + lane) * 8;\
    _Pragma("unroll")                                                             \
    for (int nt = 0; nt < 4; nt++)                                                \
      w2r[kl][nt] = *(const bf16x8*)(w2b + nt * 512);                             \
  }

// 1 block/CU by design (2 waves/SIMD): latency hidden with register-batched
// prefetch, not occupancy. LDS: Xs 64 KB + Hs dbuf 2x16 KB = 96 KB.
__global__ __launch_bounds__(512, 2) void ffn_kernel(
    const float* __restrict__ x,
    const unsigned short* __restrict__ W1p,
    const unsigned short* __restrict__ W2p,
    const float* __restrict__ b1, const float* __restrict__ b2,
    const int* __restrict__ counts,
    const int* __restrict__ tok_list, const float* __restrict__ wt_list,
    float* __restrict__ out) {
  __shared__ unsigned short Xs[64 * 512];
  __shared__ unsigned short Hs[2][64 * 128];

  const int e = blockIdx.x & 7;        // expert -> XCD pinning
  const int tile = blockIdx.x >> 3;
  const int cnt = counts[e];
  const int m0 = tile * 64;
  if (m0 >= cnt) return;
  const int rows = min(64, cnt - m0);

  const int tid = threadIdx.x;
  const int wave = tid >> 6, lane = tid & 63;
  const int g = lane >> 4, ln = lane & 15;
  const int mw = wave >> 2, nw = wave & 3;   // GEMM1 wave grid: 2(m) x 4(n)

  // stage gathered X tile (fp32 -> bf16), XOR-swizzled
  #pragma unroll 4
  for (int c = tid; c < 64 * 128; c += 512) {
    int r = c >> 7, q = c & 127;
    ushort4 bv = {0, 0, 0, 0};
    if (r < rows) {
      int tk = tok_list[e * T_TOKENS + m0 + r];
      const float4 v = *(const float4*)(x + (long)tk * DIM + q * 4);
      bv.x = f2bf(v.x); bv.y = f2bf(v.y); bv.z = f2bf(v.z); bv.w = f2bf(v.w);
    }
    int addr = r * 512 + ((((q >> 1) ^ (r & 7)) << 3) | ((q & 1) << 2));
    *(ushort4*)&Xs[addr] = bv;
  }
  __syncthreads();

  const f32x4 zero4 = {0.f, 0.f, 0.f, 0.f};
  f32x4 Yacc[4][4];
  #pragma unroll
  for (int a = 0; a < 4; a++)
    #pragma unroll
    for (int b = 0; b < 4; b++) Yacc[a][b] = zero4;

  const int xsw = ln & 7;
  const int xbase0 = (mw * 32 + ln) * 512;

  for (int fc = 0; fc < FDIM; fc += 128) {
    unsigned short* Hp = &Hs[(fc >> 7) & 1][0];
    f32x4 H00 = zero4, H01 = zero4, H10 = zero4, H11 = zero4;
    const unsigned short* w1b =
        W1p + ((long)(e * 128 + (fc >> 4) + nw * 2) * 16) * 512 + lane * 8;

    bf16x8 wA[4][2], wB[4][2], w2r[4][4];
    // software-pipelined GEMM1: load batch i+1 while MFMAing batch i
    LD_W1(wA, 0);
    LD_W1(wB, 4);
    MF_W1(wA, 0);
    LD_W1(wA, 8);
    MF_W1(wB, 4);
    LD_W1(wB, 12);
    MF_W1(wA, 8);
    LD_W2(0);          // prefetch GEMM2 kl 0,1 during GEMM1 tail
    MF_W1(wB, 12);

    // bias + relu -> Hs[p] (C-layout: col=lane&15, row=(lane>>4)*4+i)
    {
      float b1v0 = b1[e * FDIM + fc + nw * 32 + ln];
      float b1v1 = b1[e * FDIM + fc + nw * 32 + 16 + ln];
      #pragma unroll
      for (int mi = 0; mi < 2; mi++) {
        #pragma unroll
        for (int ni = 0; ni < 2; ni++) {
          const f32x4& hv = mi ? (ni ? H11 : H10) : (ni ? H01 : H00);
          float bv = ni ? b1v1 : b1v0;
          int fl = nw * 32 + ni * 16 + ln;
          #pragma unroll
          for (int i = 0; i < 4; i++) {
            int m = mw * 32 + mi * 16 + g * 4 + i;
            int addr = m * 128 + ((((fl >> 3) ^ (m & 7)) << 3) | (fl & 7));
            Hp[addr] = f2bf(fmaxf(hv[i] + bv, 0.f));
          }
        }
      }
    }
    __syncthreads();   // single barrier per fc-iter (Hs double-buffered)

    LD_W2(2);          // prefetch kl 2,3 under kl 0,1 MFMAs

    #pragma unroll
    for (int kl = 0; kl < 4; kl++) {
      bf16x8 ha[4];
      #pragma unroll
      for (int mt = 0; mt < 4; mt++) {
        int m = mt * 16 + ln;
        ha[mt] = *(const bf16x8*)&Hp[m * 128 + ((((kl * 4 + g) ^ (m & 7)) << 3))];
      }
      #pragma unroll
      for (int nt = 0; nt < 4; nt++)
        #pragma unroll
        for (int mt = 0; mt < 4; mt++)
          Yacc[mt][nt] = __builtin_amdgcn_mfma_f32_16x16x32_bf16(ha[mt], w2r[kl][nt], Yacc[mt][nt], 0, 0, 0);
    }
  }

  // epilogue: (Y + b2) * token_weight -> atomicAdd into out
  #pragma unroll
  for (int mt = 0; mt < 4; mt++) {
    #pragma unroll
    for (int i = 0; i < 4; i++) {
      int m = mt * 16 + g * 4 + i;
      if (m < rows) {
        int   tk = tok_list[e * T_TOKENS + m0 + m];
        float w  = wt_list[e * T_TOKENS + m0 + m];
        #pragma unroll
        for (int nt = 0; nt < 4; nt++) {
          int d = (wave * 4 + nt) * 16 + ln;
          float v = (Yacc[mt][nt][i] + b2[e * DIM + d]) * w;
          atomicAdd(out + (long)tk * DIM + d, v);
        }
      }
    }
  }
}

extern "C" void kernel_launch(void* const* d_in, const int* in_sizes, int n_in,
                              void* d_out, int out_size, void* d_ws, size_t ws_size,
                              hipStream_t stream) {
  (void)in_sizes; (void)n_in; (void)out_size; (void)ws_size;
  const float* x  = (const float*)d_in[0];
  const float* Wr = (const float*)d_in[1];
  const float* br = (const float*)d_in[2];
  const float* W1 = (const float*)d_in[3];
  const float* b1 = (const float*)d_in[4];
  const float* W2 = (const float*)d_in[5];
  const float* b2 = (const float*)d_in[6];
  float* out = (float*)d_out;

  char* ws = (char*)d_ws;
  int*            counts   = (int*)(ws);                      //      1,024 B
  int*            tok_list = (int*)(ws + 1024);               //  1,048,576 B
  float*          wt_list  = (float*)(ws + 1049600);          //  1,048,576 B
  unsigned short* W1p      = (unsigned short*)(ws + 2098176); // 16,777,216 B
  unsigned short* W2p      = (unsigned short*)(ws + 18875392);// 16,777,216 B  (end ~35.7 MB)

  hipMemsetAsync(counts, 0, 1024, stream);
  hipMemsetAsync(out, 0, (size_t)T_TOKENS * DIM * sizeof(float), stream);
  pack_w1_kernel<<<NEXP * 128, 256, 0, stream>>>(W1, W1p);
  pack_w2_kernel<<<NEXP * 32, 256, 0, stream>>>(W2, W2p);
  router_kernel<<<T_TOKENS / 256, 256, 0, stream>>>(x, Wr, br, counts, tok_list, wt_list);
  ffn_kernel<<<T_TOKENS / 64 * NEXP, 512, 0, stream>>>(
      x, W1p, W2p, b1, b2, counts, tok_list, wt_list, out);
}